// Round 11
// baseline (84.744 us; speedup 1.0000x reference)
//
#include <hip/hip_runtime.h>
#include <hip/hip_bf16.h>
#include <math.h>

typedef unsigned int u32;
typedef unsigned short u16;
typedef __bf16 bf16_t;
typedef bf16_t bf16x8 __attribute__((ext_vector_type(8)));
typedef float f32x4 __attribute__((ext_vector_type(4)));

#define B_N 8192
#define D_K 256
#define NCLS 360
#define NBLK 544              // sum_i ceil((128-2i)/8)
#define MAXC 61

#define SCALE2 (-20.609929155556627f)   // -(1/0.07)*log2(e)
#define LN2 (0.6931471805599453f)
#define INV_T (14.285714285714286f)     // 1/0.07

__device__ __forceinline__ float fexp2(float x) { return __builtin_amdgcn_exp2f(x); }

__device__ __forceinline__ u16 f2bf(float x) {
  u32 u = __float_as_uint(x);
  u32 r = (u + 0x7fffu + ((u >> 16) & 1u)) >> 16;
  return (u16)r;
}

__device__ __forceinline__ void gl_lds16(const void* g, void* l) {
  __builtin_amdgcn_global_load_lds(
      (const __attribute__((address_space(1))) u32*)g,
      (__attribute__((address_space(3))) u32*)l, 16, 0, 0);
}

// ---------------- K1: convert f32 -> bf16; zero the output accumulator
__global__ void k_prep(const float* __restrict__ f, u16* __restrict__ fbf,
                       float* __restrict__ out) {
  if (blockIdx.x == 0 && threadIdx.x == 0) out[0] = 0.f;
  int t = blockIdx.x * 256 + threadIdx.x;
  int e4 = t * 4;
  const float4 v = *reinterpret_cast<const float4*>(f + e4);
  ushort4 b;
  b.x = f2bf(v.x); b.y = f2bf(v.y); b.z = f2bf(v.z); b.w = f2bf(v.w);
  *reinterpret_cast<ushort4*>(fbf + e4) = b;
}

// ---------------- K2: symmetric pipelined Gram
// Block = (row-group i of 128 rows, chunk of <=8 col-tiles of 64 cols, jc>=2i).
// Round-8 skeleton: 2x32KB dbuf staging, 1 barrier/tile, online row-pass.
// Non-diagonal tiles add a col-pass (transpose partials) via 2-buffered colred.
__global__ __launch_bounds__(256, 2) void k_main(const u16* __restrict__ fb,
                                                 float2* __restrict__ part) {
  __shared__ __align__(16) u16 Bs[2][16384];   // 2 x 32KB B-tiles
  __shared__ float2 colred[2][4][64];          // 4KB col-pass merge (2-buffered)

  const int tid = threadIdx.x;
  const int lane = tid & 63;
  const int w = tid >> 6;
  const int t15 = lane & 15;
  const int g = lane >> 4;
  const int t7 = t15 & 7;

  // decode blockIdx -> (i row-group, kc chunk)
  const int bid = blockIdx.x;
  int i = 0, cum = 0;
  for (;;) {
    int ci = (135 - 2 * i) >> 3;   // ceil((128-2i)/8)
    if (bid < cum + ci) break;
    cum += ci; ++i;
  }
  const int kc = bid - cum;
  const int jc0 = 2 * i + kc * 8;
  const int nt = (128 - jc0) < 8 ? (128 - jc0) : 8;
  const int col0 = jc0 * 64;
  const int rowbase = i * 128 + w * 32;

  // A fragments: 32 rows x 256 K per wave, register resident
  bf16x8 A[2][8];
#pragma unroll
  for (int rs = 0; rs < 2; ++rs)
#pragma unroll
    for (int kk = 0; kk < 8; ++kk) {
      const u16* p = fb + (size_t)(rowbase + rs * 16 + t15) * D_K + kk * 32 + g * 8;
      A[rs][kk] = *reinterpret_cast<const bf16x8*>(p);
    }

  // hoisted staging pointers (32KB tile, 8 issues/thread)
  const u16* srcp[8];
  u16* dstp[8];
#pragma unroll
  for (int it = 0; it < 8; ++it) {
    int lin = (w * 8 + it) * 1024 + lane * 16;  // byte offset in 32KB tile
    int row = lin >> 9;                          // 512B per row
    int c = (lin >> 4) & 31;                     // 16B chunk in row
    int q = c ^ (row & 7);                       // pre-swizzled source chunk
    srcp[it] = fb + (size_t)(col0 + row) * D_K + q * 8;
    dstp[it] = &Bs[0][0] + (w * 8 + it) * 512;
  }

  // ds_read base decomposition (chunk q = (kk*4+g)^t7)
  const int gl8 = (g ^ (t7 & 3)) * 8;
  const int b2 = (t7 >> 2) & 1;
  const int offE = t15 * 256 + gl8 + b2 * 32;        // kk even
  const int offO = t15 * 256 + gl8 + (b2 ^ 1) * 32;  // kk odd

  float m2[8], Ea[8];
#pragma unroll
  for (int s = 0; s < 8; ++s) { m2[s] = -1e30f; Ea[s] = 0.f; }

#pragma unroll
  for (int it = 0; it < 8; ++it) gl_lds16(srcp[it], dstp[it]);
  __syncthreads();

  const f32x4 z4 = {0.f, 0.f, 0.f, 0.f};
  for (int t = 0; t < nt; ++t) {
    if (t + 1 < nt) {
      const int soff = (t + 1) * 16384;
      const int doff = ((t + 1) & 1) * 16384;
#pragma unroll
      for (int it = 0; it < 8; ++it) gl_lds16(srcp[it] + soff, dstp[it] + doff);
    }

    const u16* bufp = &Bs[t & 1][0];
    const u16* beE = bufp + offE;
    const u16* beO = bufp + offO;

    f32x4 C[2][4];
#pragma unroll
    for (int kk = 0; kk < 8; ++kk) {
      bf16x8 Bf[4];
#pragma unroll
      for (int s = 0; s < 4; ++s) {
        const u16* ba = (kk & 1) ? beO : beE;
        Bf[s] = *reinterpret_cast<const bf16x8*>(ba + (kk >> 1) * 64 + s * 4096);
      }
#pragma unroll
      for (int rs = 0; rs < 2; ++rs)
#pragma unroll
        for (int s = 0; s < 4; ++s)
          C[rs][s] = __builtin_amdgcn_mfma_f32_16x16x32_bf16(
              A[rs][kk], Bf[s], (kk == 0) ? z4 : C[rs][s], 0, 0, 0);
    }

    // row-pass: online max / exp-sum accumulate (positives exact in K3)
#pragma unroll
    for (int rs = 0; rs < 2; ++rs) {
#pragma unroll
      for (int q = 0; q < 4; ++q) {
        const int slot = rs * 4 + q;
        float c0 = C[rs][0][q], c1 = C[rs][1][q];
        float c2 = C[rs][2][q], c3 = C[rs][3][q];
        float tm = fminf(fminf(c0, c1), fminf(c2, c3));  // min dot = max logit
        float nm = fmaxf(m2[slot], tm * SCALE2);
        float sc = fexp2(m2[slot] - nm);
        float e0 = fexp2(fmaf(c0, SCALE2, -nm));
        float e1 = fexp2(fmaf(c1, SCALE2, -nm));
        float e2 = fexp2(fmaf(c2, SCALE2, -nm));
        float e3 = fexp2(fmaf(c3, SCALE2, -nm));
        Ea[slot] = fmaf(Ea[slot], sc, (e0 + e1) + (e2 + e3));
        m2[slot] = nm;
      }
    }

    const int jc = jc0 + t;
    const bool docol = (jc >> 1) != i;   // skip transpose on diagonal tiles
    if (docol) {
      // col-pass: per col (s*16+t15) reduce over this wave's 32 rows
#pragma unroll
      for (int s = 0; s < 4; ++s) {
        float v0 = C[0][s][0], v1 = C[0][s][1], v2 = C[0][s][2], v3 = C[0][s][3];
        float v4 = C[1][s][0], v5 = C[1][s][1], v6 = C[1][s][2], v7 = C[1][s][3];
        float m = fminf(fminf(fminf(v0, v1), fminf(v2, v3)),
                        fminf(fminf(v4, v5), fminf(v6, v7)));
        m = fminf(m, __shfl_xor(m, 16));
        m = fminf(m, __shfl_xor(m, 32));
        float mL = m * SCALE2;
        float e = ((fexp2(fmaf(v0, SCALE2, -mL)) + fexp2(fmaf(v1, SCALE2, -mL))) +
                   (fexp2(fmaf(v2, SCALE2, -mL)) + fexp2(fmaf(v3, SCALE2, -mL)))) +
                  ((fexp2(fmaf(v4, SCALE2, -mL)) + fexp2(fmaf(v5, SCALE2, -mL))) +
                   (fexp2(fmaf(v6, SCALE2, -mL)) + fexp2(fmaf(v7, SCALE2, -mL))));
        e += __shfl_xor(e, 16);
        e += __shfl_xor(e, 32);
        if (g == 0) colred[t & 1][w][s * 16 + t15] = make_float2(mL, e);
      }
    }
    __syncthreads();  // drains staging (t+1) + publishes colred[t&1]
    if (docol && tid < 64) {
      float2 p = colred[t & 1][0][tid];
      float m = p.x, e = p.y;
#pragma unroll
      for (int ww = 1; ww < 4; ++ww) {
        float2 o = colred[t & 1][ww][tid];
        float nm = fmaxf(m, o.x);
        e = e * fexp2(m - nm) + o.y * fexp2(o.x - nm);
        m = nm;
      }
      part[(size_t)i * B_N + jc * 64 + tid] = make_float2(m, e);  // slot i
    }
  }

  // row-pass final merge across the 16 column-subset lanes; slot = i + kc
#pragma unroll
  for (int st = 1; st < 16; st <<= 1) {
#pragma unroll
    for (int s = 0; s < 8; ++s) {
      float om = __shfl_xor(m2[s], st);
      float oa = __shfl_xor(Ea[s], st);
      float nm = fmaxf(m2[s], om);
      Ea[s] = Ea[s] * fexp2(m2[s] - nm) + oa * fexp2(om - nm);
      m2[s] = nm;
    }
  }
  if (t15 == 0) {
#pragma unroll
    for (int rs = 0; rs < 2; ++rs)
#pragma unroll
      for (int q = 0; q < 4; ++q) {
        int row = rowbase + rs * 16 + g * 4 + q;
        part[(size_t)(i + kc) * B_N + row] =
            make_float2(m2[rs * 4 + q], Ea[rs * 4 + q]);
      }
  }
}

// ---------------- K3: per-class exact fp32 Gram -> Ep, sum positive dots, loss
__global__ __launch_bounds__(256) void k_final(const float* __restrict__ f,
                                               const int* __restrict__ lab,
                                               const float2* __restrict__ part,
                                               float* __restrict__ out) {
  __shared__ __align__(16) float4 feat[MAXC][65];  // padded, conflict-free
  __shared__ float m2a[MAXC], Eaa[MAXC], Epa[MAXC], sda[MAXC];
  __shared__ int idx[MAXC];
  __shared__ int nS;
  const int c = blockIdx.x;
  const int tid = threadIdx.x;
  const int lane = tid & 63;
  const int w = tid >> 6;
  if (tid == 0) nS = 0;
  __syncthreads();

  for (int i = tid; i < B_N / 4; i += 256) {
    const int4 lv = reinterpret_cast<const int4*>(lab)[i];
    if (lv.x == c) { int p = atomicAdd(&nS, 1); if (p < MAXC) idx[p] = i * 4 + 0; }
    if (lv.y == c) { int p = atomicAdd(&nS, 1); if (p < MAXC) idx[p] = i * 4 + 1; }
    if (lv.z == c) { int p = atomicAdd(&nS, 1); if (p < MAXC) idx[p] = i * 4 + 2; }
    if (lv.w == c) { int p = atomicAdd(&nS, 1); if (p < MAXC) idx[p] = i * 4 + 3; }
  }
  __syncthreads();
  const int n = nS < MAXC ? nS : MAXC;

  for (int j = w; j < n; j += 4)
    feat[j][lane] = reinterpret_cast<const float4*>(f + (size_t)idx[j] * D_K)[lane];

  // merge partials: row r has cnt = jr + ceil((128-2jr)/8) valid slots (<=64)
  for (int j = w; j < n; j += 4) {
    const int r = idx[j];
    const int jr = r >> 7;
    const int cnt = jr + ((135 - 2 * jr) >> 3);
    float m2 = -1e30f, Ea = 0.f;
    if (lane < cnt) {
      float2 p = part[(size_t)lane * B_N + r];
      m2 = p.x; Ea = p.y;
    }
#pragma unroll
    for (int st = 1; st < 64; st <<= 1) {
      float om = __shfl_xor(m2, st);
      float oa = __shfl_xor(Ea, st);
      float nm = fmaxf(m2, om);
      Ea = Ea * fexp2(m2 - nm) + oa * fexp2(om - nm);
      m2 = nm;
    }
    if (lane == 0) { m2a[j] = m2; Eaa[j] = Ea; Epa[j] = 0.f; sda[j] = 0.f; }
  }
  __syncthreads();

  const int ntile = (n + 7) >> 3;
  const int jj = lane >> 3, kk = lane & 7;
  for (int tile = w; tile < ntile * ntile; tile += 4) {
    const int j = (tile / ntile) * 8 + jj;
    const int k = (tile % ntile) * 8 + kk;
    const bool ok = (j < n) && (k < n) && (j != k);
    const int jc = j < n ? j : 0, kcc = k < n ? k : 0;
    f32x4 acc = {0.f, 0.f, 0.f, 0.f};
#pragma unroll 8
    for (int d = 0; d < 64; ++d) {
      const float4 a = feat[jc][d];
      const float4 b = feat[kcc][d];
      acc[0] = fmaf(a.x, b.x, acc[0]);
      acc[1] = fmaf(a.y, b.y, acc[1]);
      acc[2] = fmaf(a.z, b.z, acc[2]);
      acc[3] = fmaf(a.w, b.w, acc[3]);
    }
    float dot = ok ? ((acc[0] + acc[1]) + (acc[2] + acc[3])) : 0.f;
    float ex = ok ? fexp2(fmaf(dot, SCALE2, -m2a[jc])) : 0.f;
#pragma unroll
    for (int st = 1; st < 8; st <<= 1) {
      dot += __shfl_xor(dot, st);
      ex += __shfl_xor(ex, st);
    }
    if (kk == 0 && j < n) {
      atomicAdd(&sda[j], dot);
      atomicAdd(&Epa[j], ex);
    }
  }
  __syncthreads();

  if (w == 0) {
    float contrib = 0.f;
    if (lane < n) {
      const int j = lane;
      float m2 = m2a[j], Ea = Eaa[j], Ep = Epa[j], sumdot = sda[j];
      float En = fmaxf(Ea - Ep, 0.f);         // self term underflows
      int cntp = n - 1;
      float cntn = (float)(B_N - 1 - cntp);
      float denom = Ep + En / (cntn + 1e-8f);
      float Sadc = -sumdot * INV_T;           // exact fp32 sum of positive logits
      float num = Sadc - (float)cntp * (m2 * LN2) - (float)cntp * logf(denom);
      float dv = (cntp <= 0) ? 1.f : (float)cntp;
      contrib = num / dv;
    }
#pragma unroll
    for (int st = 1; st < 64; st <<= 1) contrib += __shfl_xor(contrib, st);
    if (lane == 0) atomicAdd(out, contrib * (1.f / (float)B_N));
  }
}

extern "C" void kernel_launch(void* const* d_in, const int* in_sizes, int n_in,
                              void* d_out, int out_size, void* d_ws, size_t ws_size,
                              hipStream_t stream) {
  const float* f = (const float*)d_in[0];
  const int* lab = (const int*)d_in[1];

  char* ws = (char*)d_ws;
  u16* fbf = (u16*)ws;                        // 4 MB
  float2* part = (float2*)(ws + 4194304);     // 64*8192*8 = 4 MB

  k_prep<<<2048, 256, 0, stream>>>(f, fbf, (float*)d_out);
  k_main<<<NBLK, 256, 0, stream>>>(fbf, part);
  k_final<<<NCLS, 256, 0, stream>>>(f, lab, part, (float*)d_out);
}

// Round 15
// 75.662 us; speedup vs baseline: 1.1200x; 1.1200x over previous
//
#include <hip/hip_runtime.h>
#include <hip/hip_bf16.h>
#include <math.h>

typedef unsigned int u32;
typedef unsigned short u16;
typedef __bf16 bf16_t;
typedef bf16_t bf16x8 __attribute__((ext_vector_type(8)));
typedef float f32x4 __attribute__((ext_vector_type(4)));

#define B_N 8192
#define D_K 256
#define NCLS 360
#define BM 128
#define BN 64
#define NSPLIT 8
#define COLS (B_N / NSPLIT)   // 1024
#define NT (COLS / BN)        // 16
#define MAXC 61               // max class rows kept (Poisson(22.8); P(>=61) ~ 1e-12)

#define SCALE2 (-20.609929155556627f)   // -(1/0.07)*log2(e)
#define LN2 (0.6931471805599453f)
#define INV_T (14.285714285714286f)     // 1/0.07

__device__ __forceinline__ float fexp2(float x) { return __builtin_amdgcn_exp2f(x); }

__device__ __forceinline__ u16 f2bf(float x) {
  u32 u = __float_as_uint(x);
  u32 r = (u + 0x7fffu + ((u >> 16) & 1u)) >> 16;
  return (u16)r;
}

__device__ __forceinline__ void gl_lds16(const void* g, void* l) {
  __builtin_amdgcn_global_load_lds(
      (const __attribute__((address_space(1))) u32*)g,
      (__attribute__((address_space(3))) u32*)l, 16, 0, 0);
}

// ---------------- K1: f32 -> bf16 convert + class index lists + zero out
__global__ void k_prep(const float* __restrict__ f, const int* __restrict__ lab,
                       u16* __restrict__ fbf, int* __restrict__ gidx,
                       int* __restrict__ gcnt, float* __restrict__ out) {
  const int t = blockIdx.x * 256 + threadIdx.x;
  if (t == 0) out[0] = 0.f;
  const int e4 = t * 4;
  const float4 v = *reinterpret_cast<const float4*>(f + e4);
  ushort4 b;
  b.x = f2bf(v.x); b.y = f2bf(v.y); b.z = f2bf(v.z); b.w = f2bf(v.w);
  *reinterpret_cast<ushort4*>(fbf + e4) = b;
  if (t < B_N) {
    const int lb = lab[t];
    const int p = atomicAdd(&gcnt[lb], 1);
    if (p < MAXC) gidx[lb * MAXC + p] = t;
  }
}

// ---------------- K2: fused pairwise-dot + online log-sum-exp (round-8, 44.9us)
__global__ __launch_bounds__(256, 2) void k_main(const u16* __restrict__ fb,
                                                 float2* __restrict__ part) {
  __shared__ __align__(16) u16 Bs[2][16384];  // 2 x 32KB

  const int tid = threadIdx.x;
  const int lane = tid & 63;
  const int w = tid >> 6;
  const int t15 = lane & 15;
  const int g = lane >> 4;
  const int t7 = t15 & 7;
  const int rb = blockIdx.x & 63;
  const int sp = blockIdx.x >> 6;
  const int rowbase = rb * BM + w * 32;
  const int colbase = sp * COLS;

  // A fragments: 32 rows x 256 K, register resident
  bf16x8 A[2][8];
#pragma unroll
  for (int rs = 0; rs < 2; ++rs)
#pragma unroll
    for (int kk = 0; kk < 8; ++kk) {
      const u16* p = fb + (size_t)(rowbase + rs * 16 + t15) * D_K + kk * 32 + g * 8;
      A[rs][kk] = *reinterpret_cast<const bf16x8*>(p);
    }

  // hoisted staging pointers: src row/chunk pattern is tile-invariant
  const u16* srcp[8];
  u16* dstp[8];
#pragma unroll
  for (int it = 0; it < 8; ++it) {
    int lin = (w * 8 + it) * 1024 + lane * 16;  // byte offset in 32KB tile
    int row = lin >> 9;                          // 512B per row
    int c = (lin >> 4) & 31;                     // 16B chunk in row
    int q = c ^ (row & 7);                       // pre-swizzled source chunk
    srcp[it] = fb + (size_t)(colbase + row) * D_K + q * 8;
    dstp[it] = &Bs[0][0] + (w * 8 + it) * 512;
  }

  // ds_read base decomposition (chunk q = (kk*4+g)^t7)
  const int gl8 = (g ^ (t7 & 3)) * 8;
  const int b2 = (t7 >> 2) & 1;
  const int offE = t15 * 256 + gl8 + b2 * 32;        // kk even
  const int offO = t15 * 256 + gl8 + (b2 ^ 1) * 32;  // kk odd

  float m2[8], Ea[8];
#pragma unroll
  for (int i = 0; i < 8; ++i) { m2[i] = -1e30f; Ea[i] = 0.f; }

#pragma unroll
  for (int it = 0; it < 8; ++it) gl_lds16(srcp[it], dstp[it]);
  __syncthreads();

  const f32x4 z4 = {0.f, 0.f, 0.f, 0.f};
  for (int t = 0; t < NT; ++t) {
    if (t + 1 < NT) {
      const int soff = (t + 1) * (BN * D_K);
      const int doff = ((t + 1) & 1) * (BN * D_K);
#pragma unroll
      for (int it = 0; it < 8; ++it) gl_lds16(srcp[it] + soff, dstp[it] + doff);
    }

    const u16* bufp = &Bs[t & 1][0];
    const u16* beE = bufp + offE;
    const u16* beO = bufp + offO;

    f32x4 C[2][4];
#pragma unroll
    for (int kk = 0; kk < 8; ++kk) {
      bf16x8 Bf[4];
#pragma unroll
      for (int s = 0; s < 4; ++s) {
        const u16* ba = (kk & 1) ? beO : beE;
        Bf[s] = *reinterpret_cast<const bf16x8*>(ba + (kk >> 1) * 64 + s * 4096);
      }
#pragma unroll
      for (int rs = 0; rs < 2; ++rs)
#pragma unroll
        for (int s = 0; s < 4; ++s)
          C[rs][s] = __builtin_amdgcn_mfma_f32_16x16x32_bf16(
              A[rs][kk], Bf[s], (kk == 0) ? z4 : C[rs][s], 0, 0, 0);
    }

    // slim epilogue: online max / exp-sum only (positives exact in K3)
#pragma unroll
    for (int rs = 0; rs < 2; ++rs) {
#pragma unroll
      for (int q = 0; q < 4; ++q) {
        const int slot = rs * 4 + q;
        float c0 = C[rs][0][q], c1 = C[rs][1][q];
        float c2 = C[rs][2][q], c3 = C[rs][3][q];
        float tm = fminf(fminf(c0, c1), fminf(c2, c3));  // min dot = max logit
        float nm = fmaxf(m2[slot], tm * SCALE2);
        float sc = fexp2(m2[slot] - nm);
        float e0 = fexp2(fmaf(c0, SCALE2, -nm));
        float e1 = fexp2(fmaf(c1, SCALE2, -nm));
        float e2 = fexp2(fmaf(c2, SCALE2, -nm));
        float e3 = fexp2(fmaf(c3, SCALE2, -nm));
        Ea[slot] = fmaf(Ea[slot], sc, (e0 + e1) + (e2 + e3));
        m2[slot] = nm;
      }
    }
    __syncthreads();
  }

  // cross-lane merge across the 16 column-subset lanes
#pragma unroll
  for (int st = 1; st < 16; st <<= 1) {
#pragma unroll
    for (int i = 0; i < 8; ++i) {
      float om = __shfl_xor(m2[i], st);
      float oa = __shfl_xor(Ea[i], st);
      float nm = fmaxf(m2[i], om);
      Ea[i] = Ea[i] * fexp2(m2[i] - nm) + oa * fexp2(om - nm);
      m2[i] = nm;
    }
  }
  if (t15 == 0) {
#pragma unroll
    for (int rs = 0; rs < 2; ++rs)
#pragma unroll
      for (int q = 0; q < 4; ++q) {
        int row = rowbase + rs * 16 + g * 4 + q;
        part[sp * B_N + row] = make_float2(m2[rs * 4 + q], Ea[rs * 4 + q]);
      }
  }
}

// ---------------- K3: per-class exact fp32 Gram -> Ep, sum positive dots, loss
__global__ __launch_bounds__(256) void k_final(const float* __restrict__ f,
                                               const int* __restrict__ gidx,
                                               const int* __restrict__ gcnt,
                                               const float2* __restrict__ part,
                                               float* __restrict__ out) {
  __shared__ __align__(16) float4 feat[MAXC][65];  // padded, conflict-free
  __shared__ float m2a[MAXC], Eaa[MAXC], Epa[MAXC], sda[MAXC];
  const int c = blockIdx.x;
  const int tid = threadIdx.x;
  const int lane = tid & 63;
  const int w = tid >> 6;

  const int n0 = gcnt[c];
  const int n = n0 < MAXC ? n0 : MAXC;

  // load class rows into LDS (fp32, coalesced 1KB per row)
  for (int j = w; j < n; j += 4)
    feat[j][lane] =
        reinterpret_cast<const float4*>(f + (size_t)gidx[c * MAXC + j] * D_K)[lane];

  // merge the NSPLIT partials per row (lanes 0..7 hold one split each)
  for (int j = w; j < n; j += 4) {
    float m2 = -1e30f, Ea = 0.f;
    if (lane < NSPLIT) {
      float2 p = part[lane * B_N + gidx[c * MAXC + j]];
      m2 = p.x; Ea = p.y;
    }
#pragma unroll
    for (int st = 1; st < NSPLIT; st <<= 1) {
      float om = __shfl_xor(m2, st);
      float oa = __shfl_xor(Ea, st);
      float nm = fmaxf(m2, om);
      Ea = Ea * fexp2(m2 - nm) + oa * fexp2(om - nm);
      m2 = nm;
    }
    if (lane == 0) { m2a[j] = m2; Eaa[j] = Ea; Epa[j] = 0.f; sda[j] = 0.f; }
  }
  __syncthreads();

  // Gram tiles: 8x8 pairs per wave-tile, one pair per lane
  const int ntile = (n + 7) >> 3;
  const int jj = lane >> 3, kk = lane & 7;
  for (int tile = w; tile < ntile * ntile; tile += 4) {
    const int j = (tile / ntile) * 8 + jj;
    const int k = (tile % ntile) * 8 + kk;
    const bool ok = (j < n) && (k < n) && (j != k);
    const int jc = j < n ? j : 0, kc = k < n ? k : 0;
    f32x4 acc = {0.f, 0.f, 0.f, 0.f};
#pragma unroll 8
    for (int d = 0; d < 64; ++d) {
      const float4 a = feat[jc][d];
      const float4 b = feat[kc][d];
      acc[0] = fmaf(a.x, b.x, acc[0]);
      acc[1] = fmaf(a.y, b.y, acc[1]);
      acc[2] = fmaf(a.z, b.z, acc[2]);
      acc[3] = fmaf(a.w, b.w, acc[3]);
    }
    float dot = ok ? ((acc[0] + acc[1]) + (acc[2] + acc[3])) : 0.f;
    float ex = ok ? fexp2(fmaf(dot, SCALE2, -m2a[jc])) : 0.f;
#pragma unroll
    for (int st = 1; st < 8; st <<= 1) {
      dot += __shfl_xor(dot, st);
      ex += __shfl_xor(ex, st);
    }
    if (kk == 0 && j < n) {
      atomicAdd(&sda[j], dot);
      atomicAdd(&Epa[j], ex);
    }
  }
  __syncthreads();

  // finalize rows of this class, reduce, one atomic per block
  if (w == 0) {
    float contrib = 0.f;
    if (lane < n) {
      const int j = lane;
      float m2 = m2a[j], Ea = Eaa[j], Ep = Epa[j], sumdot = sda[j];
      float En = fmaxf(Ea - Ep, 0.f);         // self term underflows
      int cntp = n - 1;
      float cntn = (float)(B_N - 1 - cntp);
      float denom = Ep + En / (cntn + 1e-8f);
      float Sadc = -sumdot * INV_T;           // exact fp32 sum of positive logits
      float num = Sadc - (float)cntp * (m2 * LN2) - (float)cntp * logf(denom);
      float dv = (cntp <= 0) ? 1.f : (float)cntp;
      contrib = num / dv;
    }
#pragma unroll
    for (int st = 1; st < 64; st <<= 1) contrib += __shfl_xor(contrib, st);
    if (lane == 0) atomicAdd(out, contrib * (1.f / (float)B_N));
  }
}

extern "C" void kernel_launch(void* const* d_in, const int* in_sizes, int n_in,
                              void* d_out, int out_size, void* d_ws, size_t ws_size,
                              hipStream_t stream) {
  const float* f = (const float*)d_in[0];
  const int* lab = (const int*)d_in[1];

  char* ws = (char*)d_ws;
  u16* fbf = (u16*)ws;                                    // 4 MB
  float2* part = (float2*)(ws + 4194304);                 // 512 KB
  int* gidx = (int*)(ws + 4194304 + 524288);              // 360*61*4 = 87,840 B
  int* gcnt = (int*)(ws + 4194304 + 524288 + 88064);      // 1440 B

  (void)hipMemsetAsync(gcnt, 0, NCLS * sizeof(int), stream);
  k_prep<<<2048, 256, 0, stream>>>(f, lab, fbf, gidx, gcnt, (float*)d_out);
  k_main<<<64 * NSPLIT, 256, 0, stream>>>(fbf, part);
  k_final<<<NCLS, 256, 0, stream>>>(f, gidx, gcnt, part, (float*)d_out);
}